// Round 13
// baseline (470.418 us; speedup 1.0000x reference)
//
#include <hip/hip_runtime.h>

#define NROW 10000
#define NF 256
#define KF 512
#define MPK 10240   // 40*256, padded K extent for hsT / gemm
#define NKT 40      // K-tiles of 256
#define NTILES 157  // M-tiles of 64

typedef __attribute__((ext_vector_type(8))) short short8x;
typedef __attribute__((ext_vector_type(4))) float f32x4;

__device__ __forceinline__ unsigned int bf16rne(float f){
  unsigned int u = __builtin_bit_cast(unsigned int, f);
  u += 0x7fffu + ((u >> 16) & 1u);   // round-to-nearest-even
  return u >> 16;
}

// ---------------- Kernel 0: zero d_out (atomic accumulation target)
__global__ void k_zero(float4* __restrict__ p){
  p[blockIdx.x * 256 + threadIdx.x] = make_float4(0.f, 0.f, 0.f, 0.f);
}

// ---------------- k_deg2 (UNCHANGED, measured 64us): one wave per FULL row.
__global__ __launch_bounds__(256) void k_deg2(const float* __restrict__ adj,
        float* __restrict__ degp){
  int t = threadIdx.x;
  int lane = t & 63;
  int row = blockIdx.x * 4 + (t >> 6);          // 2500*4 = 10000 exact
  const f32x4* src = (const f32x4*)(adj + (size_t)row * NROW);  // 2500 slots/row
  const f32x4 zero4 = {0.f, 0.f, 0.f, 0.f};
  f32x4 acc0 = zero4, acc1 = zero4;
  f32x4 v[8];
  #pragma unroll
  for (int it = 0; it < 4; ++it){               // slots [0, 2048)
    int base = it * 512 + lane;
    #pragma unroll
    for (int b = 0; b < 8; ++b) v[b] = src[base + b * 64];
    #pragma unroll
    for (int b = 0; b < 4; ++b){ acc0 += v[2*b]; acc1 += v[2*b + 1]; }
  }
  {                                             // tail: slots [2048, 2500)
    int base = 2048 + lane;
    #pragma unroll
    for (int b = 0; b < 8; ++b){
      int fi = base + b * 64;
      v[b] = (fi < 2500) ? src[fi] : zero4;
    }
    #pragma unroll
    for (int b = 0; b < 4; ++b){ acc0 += v[2*b]; acc1 += v[2*b + 1]; }
  }
  f32x4 a = acc0 + acc1;
  float s = (a[0] + a[1]) + (a[2] + a[3]);
  #pragma unroll
  for (int off = 32; off; off >>= 1) s += __shfl_down(s, off);
  if (lane == 0) degp[row] = s;                 // full raw row sum
}

// ---------------- k_dinv: dinv[i] = rsqrt(rawsum - adj[i][i] + 1);
// also zeroes hsT K-tail rows [10000,10240) for the gemm B-operand.
__global__ void k_dinv(const float* __restrict__ degp, const float* __restrict__ adj,
                       float* __restrict__ dinv, unsigned short* __restrict__ hsT){
  int i = blockIdx.x * 256 + threadIdx.x;
  if (i >= MPK) return;
  float d = 0.f;
  if (i < NROW){
    float tot = degp[i] + 1.0f - adj[(size_t)i * NROW + i];   // diag patched to 1
    d = tot > 0.f ? rsqrtf(tot) : 0.f;
  }
  if (i < MPK) dinv[i] = d;
  if (i < NF){
    unsigned int* tz = (unsigned int*)(hsT + (size_t)i * MPK + NROW);
    #pragma unroll
    for (int m = 0; m < (MPK - NROW) / 2; ++m) tz[m] = 0u;
  }
}

// ---------------- k_featw: hsT[c][i] = bf16(dinv[i]*(feat@W)[i][c])
// (same as R11 except hsT stride MPK)
__global__ __launch_bounds__(128) void k_featw(const float* __restrict__ feat,
        const float* __restrict__ W, const float* __restrict__ dinv,
        unsigned short* __restrict__ hsT){
  __shared__ __align__(16) float fs[8][512];   // 16 KB
  int t = threadIdx.x;        // 0..127
  int i0 = blockIdx.x * 8;    // 1250*8 = 10000 exact
  #pragma unroll
  for (int it = 0; it < 8; ++it){
    int idx = it * 128 + t;
    int r = idx >> 7, c4 = (idx & 127) * 4;
    *(float4*)&fs[r][c4] = *(const float4*)(feat + (size_t)(i0 + r) * KF + c4);
  }
  __syncthreads();
  float acc[8][2];
  #pragma unroll
  for (int r = 0; r < 8; ++r){ acc[r][0] = 0.f; acc[r][1] = 0.f; }
  int c0 = t, c1 = t + 128;
  for (int k = 0; k < KF; k += 4){
    const float* Wk = W + (size_t)k * NF;
    float w0a = Wk[c0],        w0b = Wk[c1];
    float w1a = Wk[NF + c0],   w1b = Wk[NF + c1];
    float w2a = Wk[2*NF + c0], w2b = Wk[2*NF + c1];
    float w3a = Wk[3*NF + c0], w3b = Wk[3*NF + c1];
    #pragma unroll
    for (int r = 0; r < 8; ++r){
      float4 f = *(const float4*)&fs[r][k];
      float a0 = acc[r][0], a1 = acc[r][1];
      a0 = fmaf(f.x, w0a, a0); a1 = fmaf(f.x, w0b, a1);
      a0 = fmaf(f.y, w1a, a0); a1 = fmaf(f.y, w1b, a1);
      a0 = fmaf(f.z, w2a, a0); a1 = fmaf(f.z, w2b, a1);
      a0 = fmaf(f.w, w3a, a0); a1 = fmaf(f.w, w3b, a1);
      acc[r][0] = a0; acc[r][1] = a1;
    }
  }
  float dv[8];
  #pragma unroll
  for (int r = 0; r < 8; ++r) dv[r] = dinv[i0 + r];
  unsigned short* d0 = hsT + (size_t)c0 * MPK + i0;
  unsigned short* d1 = hsT + (size_t)c1 * MPK + i0;
  #pragma unroll
  for (int r = 0; r < 8; r += 2){
    unsigned int u0 = bf16rne(acc[r][0] * dv[r]) | (bf16rne(acc[r+1][0] * dv[r+1]) << 16);
    unsigned int u1 = bf16rne(acc[r][1] * dv[r]) | (bf16rne(acc[r+1][1] * dv[r+1]) << 16);
    *(unsigned int*)(d0 + r) = u0;
    *(unsigned int*)(d1 + r) = u1;
  }
}

// ---------------- k_gemm (RESTRUCTURED for A-read BW):
// BK=256: 1 KB contiguous per row per stage (4x the DRAM burst), barriers
// 4x less frequent. B read per-fragment from global (hsT L2/L3-resident,
// clean 64B lines) -> LDS holds only A (33 KB) -> 4 blocks/CU, all 628
// blocks co-resident. K split 4-ways, atomic accumulate.
__global__ __launch_bounds__(256, 4) void k_gemm(const float* __restrict__ adj,
        const unsigned short* __restrict__ hsT, float* __restrict__ out){
  __shared__ __align__(16) unsigned short Al[64][264];   // +8 pad, 528B stride
  int t = threadIdx.x;
  int lane = t & 63, wid = t >> 6;
  int wr = wid >> 1, wc = wid & 1;      // 2x2 waves, wave tile 32x128
  int l15 = lane & 15, hi = lane >> 4;
  int r0 = blockIdx.x * 64;
  int kt0 = blockIdx.y * (NKT/4);       // 10 K-tiles of 256 per block
  int kt1 = kt0 + (NKT/4);

  f32x4 acc[2][8];
  #pragma unroll
  for (int a = 0; a < 2; ++a)
    #pragma unroll
    for (int b = 0; b < 8; ++b)
      #pragma unroll
      for (int j = 0; j < 4; ++j) acc[a][b][j] = 0.f;

  int srow = t >> 4;          // 0..15
  int scol = (t & 15) * 4;    // f32 col 0..60 within 64-col quarter
  const unsigned short* bbase = hsT + (size_t)(wc*128 + l15) * MPK;

  for (int kt = kt0; kt < kt1; ++kt){
    int k0 = kt * 256;
    // ---- stage A: 64 rows x 256 f32 -> bf16. Per row-group, 4 quarters
    // issued back-to-back => 1 KB temporally-clustered burst per row.
    #pragma unroll
    for (int it = 0; it < 4; ++it){
      int row = it * 16 + srow;
      int gr  = r0 + row;
      int er  = gr < NROW ? gr : NROW - 1;        // pad rows dropped at store
      const float* rowp = adj + (size_t)er * NROW;
      #pragma unroll
      for (int j = 0; j < 4; ++j){
        int gcb = k0 + scol + j * 64;
        int ec  = gcb <= NROW - 4 ? gcb : NROW - 4;  // tail cols: B==0 anyway
        float4 v = *(const float4*)(rowp + ec);
        float f0 = v.x, f1 = v.y, f2 = v.z, f3 = v.w;
        if (gr == gcb    ) f0 = 1.f;
        if (gr == gcb + 1) f1 = 1.f;
        if (gr == gcb + 2) f2 = 1.f;
        if (gr == gcb + 3) f3 = 1.f;
        unsigned int u0 = bf16rne(f0) | (bf16rne(f1) << 16);
        unsigned int u1 = bf16rne(f2) | (bf16rne(f3) << 16);
        *(uint2*)&Al[row][scol + j * 64] = make_uint2(u0, u1);
      }
    }
    __syncthreads();
    // ---- MFMA over the 256-wide tile; B fragments straight from L2/L3
    #pragma unroll
    for (int k8 = 0; k8 < 8; ++k8){
      short8x a0 = *(const short8x*)&Al[wr*32      + l15][k8*32 + hi*8];
      short8x a1 = *(const short8x*)&Al[wr*32 + 16 + l15][k8*32 + hi*8];
      const unsigned short* bk = bbase + k0 + k8*32 + hi*8;
      #pragma unroll
      for (int ni = 0; ni < 8; ++ni){
        short8x b = *(const short8x*)(bk + (size_t)ni * 16 * MPK);
        acc[0][ni] = __builtin_amdgcn_mfma_f32_16x16x32_bf16(a0, b, acc[0][ni], 0, 0, 0);
        acc[1][ni] = __builtin_amdgcn_mfma_f32_16x16x32_bf16(a1, b, acc[1][ni], 0, 0, 0);
      }
    }
    __syncthreads();
  }
  // ---- epilogue: atomic accumulate partial K-sums (4 commutative adds/elem)
  #pragma unroll
  for (int mi = 0; mi < 2; ++mi){
    #pragma unroll
    for (int ni = 0; ni < 8; ++ni){
      int gc = wc*128 + ni*16 + l15;
      #pragma unroll
      for (int j = 0; j < 4; ++j){
        int gr = r0 + wr*32 + mi*16 + hi*4 + j;
        if (gr < NROW) atomicAdd(out + (size_t)gr * NF + gc, acc[mi][ni][j]);
      }
    }
  }
}

// ---------------- k_epi: out = relu(dinv_i * acc + cb + eb), in place
__global__ void k_epi(float* __restrict__ out, const float* __restrict__ dinv,
                      const float* __restrict__ cb, const float* __restrict__ eb){
  int e = (blockIdx.x * 256 + threadIdx.x) * 4;
  int i = e >> 8, c = e & 255;
  float di = dinv[i];
  float4 v = *(float4*)(out + e);
  v.x = fmaxf(fmaf(v.x, di, cb[c+0] + eb[c+0]), 0.f);
  v.y = fmaxf(fmaf(v.y, di, cb[c+1] + eb[c+1]), 0.f);
  v.z = fmaxf(fmaf(v.z, di, cb[c+2] + eb[c+2]), 0.f);
  v.w = fmaxf(fmaf(v.w, di, cb[c+3] + eb[c+3]), 0.f);
  *(float4*)(out + e) = v;
}

extern "C" void kernel_launch(void* const* d_in, const int* in_sizes, int n_in,
                              void* d_out, int out_size, void* d_ws, size_t ws_size,
                              hipStream_t stream){
  const float* feat = (const float*)d_in[0];
  const float* adj  = (const float*)d_in[1];
  const float* W    = (const float*)d_in[2];
  const float* cb   = (const float*)d_in[3];
  const float* eb   = (const float*)d_in[4];
  float* out = (float*)d_out;

  // ws layout: degp f32[10240] @0 ; dinv f32[10240] @256KB ;
  //            hsT bf16[256][10240] @512KB (5.25 MB).
  float* degp = (float*)d_ws;
  float* dinv = (float*)((char*)d_ws + (256u << 10));
  unsigned short* hsT = (unsigned short*)((char*)d_ws + (512u << 10));

  k_zero <<<(NROW*NF)/1024,   256, 0, stream>>>((float4*)out);
  k_deg2 <<<NROW/4,           256, 0, stream>>>(adj, degp);
  k_dinv <<<(MPK + 255)/256,  256, 0, stream>>>(degp, adj, dinv, hsT);
  k_featw<<<NROW/8,           128, 0, stream>>>(feat, W, dinv, hsT);
  k_gemm <<<dim3(NTILES, 4),  256, 0, stream>>>(adj, hsT, out);
  k_epi  <<<(NROW*NF)/1024,   256, 0, stream>>>(out, dinv, cb, eb);
}

// Round 14
// 321.596 us; speedup vs baseline: 1.4628x; 1.4628x over previous
//
#include <hip/hip_runtime.h>

#define NROW 10000
#define NF 256
#define KF 512
#define MP 10048    // 157*64, padded K extent
#define NT32 313    // M-tiles of 32 (313*32 = 10016)
#define NKT 157     // K-tiles of 64

typedef __attribute__((ext_vector_type(8))) short short8x;
typedef __attribute__((ext_vector_type(4))) float f32x4;

__device__ __forceinline__ unsigned int bf16rne(float f){
  unsigned int u = __builtin_bit_cast(unsigned int, f);
  u += 0x7fffu + ((u >> 16) & 1u);   // round-to-nearest-even
  return u >> 16;
}

// ---------------- Kernel 0: zero d_out (atomic accumulation target)
__global__ void k_zero(float4* __restrict__ p){
  p[blockIdx.x * 256 + threadIdx.x] = make_float4(0.f, 0.f, 0.f, 0.f);
}

// ---------------- k_deg2 (UNCHANGED, measured 64us): one wave per FULL row.
__global__ __launch_bounds__(256) void k_deg2(const float* __restrict__ adj,
        float* __restrict__ degp){
  int t = threadIdx.x;
  int lane = t & 63;
  int row = blockIdx.x * 4 + (t >> 6);          // 2500*4 = 10000 exact
  const f32x4* src = (const f32x4*)(adj + (size_t)row * NROW);  // 2500 slots/row
  const f32x4 zero4 = {0.f, 0.f, 0.f, 0.f};
  f32x4 acc0 = zero4, acc1 = zero4;
  f32x4 v[8];
  #pragma unroll
  for (int it = 0; it < 4; ++it){               // slots [0, 2048)
    int base = it * 512 + lane;
    #pragma unroll
    for (int b = 0; b < 8; ++b) v[b] = src[base + b * 64];
    #pragma unroll
    for (int b = 0; b < 4; ++b){ acc0 += v[2*b]; acc1 += v[2*b + 1]; }
  }
  {                                             // tail: slots [2048, 2500)
    int base = 2048 + lane;
    #pragma unroll
    for (int b = 0; b < 8; ++b){
      int fi = base + b * 64;
      v[b] = (fi < 2500) ? src[fi] : zero4;
    }
    #pragma unroll
    for (int b = 0; b < 4; ++b){ acc0 += v[2*b]; acc1 += v[2*b + 1]; }
  }
  f32x4 a = acc0 + acc1;
  float s = (a[0] + a[1]) + (a[2] + a[3]);
  #pragma unroll
  for (int off = 32; off; off >>= 1) s += __shfl_down(s, off);
  if (lane == 0) degp[row] = s;                 // full raw row sum
}

// ---------------- k_dinv: dinv[i] = rsqrt(rawsum - adj[i][i] + 1);
// also zeroes hsT K-tail rows [10000,10048).
__global__ void k_dinv(const float* __restrict__ degp, const float* __restrict__ adj,
                       float* __restrict__ dinv, unsigned short* __restrict__ hsT){
  int i = blockIdx.x * 256 + threadIdx.x;
  if (i >= MP) return;
  float d = 0.f;
  if (i < NROW){
    float tot = degp[i] + 1.0f - adj[(size_t)i * NROW + i];   // diag patched to 1
    d = tot > 0.f ? rsqrtf(tot) : 0.f;
  }
  dinv[i] = d;
  if (i < NF){
    unsigned int* tz = (unsigned int*)(hsT + (size_t)i * MP + NROW);
    #pragma unroll
    for (int m = 0; m < (MP - NROW) / 2; ++m) tz[m] = 0u;
  }
}

// ---------------- k_featw (UNCHANGED): hsT[c][i] = bf16(dinv[i]*(feat@W)[i][c])
__global__ __launch_bounds__(128) void k_featw(const float* __restrict__ feat,
        const float* __restrict__ W, const float* __restrict__ dinv,
        unsigned short* __restrict__ hsT){
  __shared__ __align__(16) float fs[8][512];   // 16 KB
  int t = threadIdx.x;        // 0..127
  int i0 = blockIdx.x * 8;    // 1250*8 = 10000 exact
  #pragma unroll
  for (int it = 0; it < 8; ++it){
    int idx = it * 128 + t;
    int r = idx >> 7, c4 = (idx & 127) * 4;
    *(float4*)&fs[r][c4] = *(const float4*)(feat + (size_t)(i0 + r) * KF + c4);
  }
  __syncthreads();
  float acc[8][2];
  #pragma unroll
  for (int r = 0; r < 8; ++r){ acc[r][0] = 0.f; acc[r][1] = 0.f; }
  int c0 = t, c1 = t + 128;
  for (int k = 0; k < KF; k += 4){
    const float* Wk = W + (size_t)k * NF;
    float w0a = Wk[c0],        w0b = Wk[c1];
    float w1a = Wk[NF + c0],   w1b = Wk[NF + c1];
    float w2a = Wk[2*NF + c0], w2b = Wk[2*NF + c1];
    float w3a = Wk[3*NF + c0], w3b = Wk[3*NF + c1];
    #pragma unroll
    for (int r = 0; r < 8; ++r){
      float4 f = *(const float4*)&fs[r][k];
      float a0 = acc[r][0], a1 = acc[r][1];
      a0 = fmaf(f.x, w0a, a0); a1 = fmaf(f.x, w0b, a1);
      a0 = fmaf(f.y, w1a, a0); a1 = fmaf(f.y, w1b, a1);
      a0 = fmaf(f.z, w2a, a0); a1 = fmaf(f.z, w2b, a1);
      a0 = fmaf(f.w, w3a, a0); a1 = fmaf(f.w, w3b, a1);
      acc[r][0] = a0; acc[r][1] = a1;
    }
  }
  float dv[8];
  #pragma unroll
  for (int r = 0; r < 8; ++r) dv[r] = dinv[i0 + r];
  unsigned short* d0 = hsT + (size_t)c0 * MP + i0;
  unsigned short* d1 = hsT + (size_t)c1 * MP + i0;
  #pragma unroll
  for (int r = 0; r < 8; r += 2){
    unsigned int u0 = bf16rne(acc[r][0] * dv[r]) | (bf16rne(acc[r+1][0] * dv[r+1]) << 16);
    unsigned int u1 = bf16rne(acc[r][1] * dv[r]) | (bf16rne(acc[r+1][1] * dv[r+1]) << 16);
    *(unsigned int*)(d0 + r) = u0;
    *(unsigned int*)(d1 + r) = u1;
  }
}

// ---------------- k_gemm: R10 structure, re-tiled for overlap + fewer atomics.
// BM=32 (626 blocks, ~2.4/CU with capacity 3): desynchronized blocks keep the
// A-stream in flight while others sit at barriers (R10 had 2 lock-step
// blocks/CU). KSPLIT=2 halves atomic write-through (~150 MB HBM writes saved).
// B LDS-staged (R13 lesson: per-fragment global B-gather is latency death).
__global__ __launch_bounds__(256, 3) void k_gemm(const float* __restrict__ adj,
        const unsigned short* __restrict__ hsT, float* __restrict__ out){
  __shared__ __align__(16) unsigned short Al[32][72];    // +8 pad: 144B stride
  __shared__ __align__(16) unsigned short Bl[256][72];
  int t = threadIdx.x;
  int lane = t & 63, wid = t >> 6;
  int l15 = lane & 15, hi = lane >> 4;
  int r0 = blockIdx.x * 32;
  int kt0 = blockIdx.y * 78;            // K halves: [0,79) and [78.. wait
  // K split: by=0 -> tiles [0,79), by=1 -> [79,157)
  kt0 = blockIdx.y ? 79 : 0;
  int kt1 = blockIdx.y ? NKT : 79;

  f32x4 acc[2][4];
  #pragma unroll
  for (int a = 0; a < 2; ++a)
    #pragma unroll
    for (int b = 0; b < 4; ++b)
      #pragma unroll
      for (int j = 0; j < 4; ++j) acc[a][b][j] = 0.f;

  int arow = t >> 4;          // 0..15 (two row-groups of 16)
  int acol = (t & 15) * 4;    // 0..60
  int bcol = t >> 3;          // 0..31
  int bko  = (t & 7) * 8;     // 0..56

  for (int kt = kt0; kt < kt1; ++kt){
    int k0 = kt * 64;
    // ---- stage A tile 32x64 (f32 -> bf16, diag patched, clamped tail)
    #pragma unroll
    for (int it = 0; it < 2; ++it){
      int row = it * 16 + arow;
      int gr  = r0 + row;
      int gcb = k0 + acol;
      int er = gr  < NROW      ? gr  : NROW - 1;   // pad rows dropped at store
      int ec = gcb <= NROW - 4 ? gcb : NROW - 4;   // tail cols: B rows are 0
      float4 v = *(const float4*)(adj + (size_t)er * NROW + ec);
      float f0 = v.x, f1 = v.y, f2 = v.z, f3 = v.w;
      if (gr == gcb    ) f0 = 1.f;
      if (gr == gcb + 1) f1 = 1.f;
      if (gr == gcb + 2) f2 = 1.f;
      if (gr == gcb + 3) f3 = 1.f;
      unsigned int u0 = bf16rne(f0) | (bf16rne(f1) << 16);
      unsigned int u1 = bf16rne(f2) | (bf16rne(f3) << 16);
      *(uint2*)&Al[row][acol] = make_uint2(u0, u1);
    }
    // ---- stage B tile 256x64 (bf16 copy; K-tail rows pre-zeroed)
    #pragma unroll
    for (int it = 0; it < 8; ++it){
      int cc = it * 32 + bcol;
      *(uint4*)&Bl[cc][bko] = *(const uint4*)(hsT + (size_t)cc * MP + k0 + bko);
    }
    __syncthreads();
    // ---- MFMA: 2x4 fragments of 16x16 per wave (wave tile 32x64)
    #pragma unroll
    for (int kk = 0; kk < 64; kk += 32){
      short8x a0 = *(const short8x*)&Al[l15     ][kk + hi * 8];
      short8x a1 = *(const short8x*)&Al[l15 + 16][kk + hi * 8];
      #pragma unroll
      for (int ni = 0; ni < 4; ++ni){
        short8x b = *(const short8x*)&Bl[wid*64 + ni*16 + l15][kk + hi * 8];
        acc[0][ni] = __builtin_amdgcn_mfma_f32_16x16x32_bf16(a0, b, acc[0][ni], 0, 0, 0);
        acc[1][ni] = __builtin_amdgcn_mfma_f32_16x16x32_bf16(a1, b, acc[1][ni], 0, 0, 0);
      }
    }
    __syncthreads();
  }
  // ---- epilogue: atomic accumulate partial K-sums (2 commutative adds/elem)
  #pragma unroll
  for (int mi = 0; mi < 2; ++mi){
    #pragma unroll
    for (int ni = 0; ni < 4; ++ni){
      int gc = wid*64 + ni*16 + l15;
      #pragma unroll
      for (int j = 0; j < 4; ++j){
        int gr = r0 + mi*16 + hi*4 + j;
        if (gr < NROW) atomicAdd(out + (size_t)gr * NF + gc, acc[mi][ni][j]);
      }
    }
  }
}

// ---------------- k_epi: out = relu(dinv_i * acc + cb + eb), in place
__global__ void k_epi(float* __restrict__ out, const float* __restrict__ dinv,
                      const float* __restrict__ cb, const float* __restrict__ eb){
  int e = (blockIdx.x * 256 + threadIdx.x) * 4;
  int i = e >> 8, c = e & 255;
  float di = dinv[i];
  float4 v = *(float4*)(out + e);
  v.x = fmaxf(fmaf(v.x, di, cb[c+0] + eb[c+0]), 0.f);
  v.y = fmaxf(fmaf(v.y, di, cb[c+1] + eb[c+1]), 0.f);
  v.z = fmaxf(fmaf(v.z, di, cb[c+2] + eb[c+2]), 0.f);
  v.w = fmaxf(fmaf(v.w, di, cb[c+3] + eb[c+3]), 0.f);
  *(float4*)(out + e) = v;
}

extern "C" void kernel_launch(void* const* d_in, const int* in_sizes, int n_in,
                              void* d_out, int out_size, void* d_ws, size_t ws_size,
                              hipStream_t stream){
  const float* feat = (const float*)d_in[0];
  const float* adj  = (const float*)d_in[1];
  const float* W    = (const float*)d_in[2];
  const float* cb   = (const float*)d_in[3];
  const float* eb   = (const float*)d_in[4];
  float* out = (float*)d_out;

  // ws layout: degp f32[10048] @0 ; dinv f32[10048] @256KB ;
  //            hsT bf16[256][10048] @512KB (5.1 MB).
  float* degp = (float*)d_ws;
  float* dinv = (float*)((char*)d_ws + (256u << 10));
  unsigned short* hsT = (unsigned short*)((char*)d_ws + (512u << 10));

  k_zero <<<(NROW*NF)/1024,  256, 0, stream>>>((float4*)out);
  k_deg2 <<<NROW/4,          256, 0, stream>>>(adj, degp);
  k_dinv <<<(MP + 255)/256,  256, 0, stream>>>(degp, adj, dinv, hsT);
  k_featw<<<NROW/8,          128, 0, stream>>>(feat, W, dinv, hsT);
  k_gemm <<<dim3(NT32, 2),   256, 0, stream>>>(adj, hsT, out);
  k_epi  <<<(NROW*NF)/1024,  256, 0, stream>>>(out, dinv, cb, eb);
}

// Round 15
// 318.347 us; speedup vs baseline: 1.4777x; 1.0102x over previous
//
#include <hip/hip_runtime.h>

#define NROW 10000
#define NF 256
#define KF 512
#define MP 10048    // padded row/K extent
#define NKT 157     // K-tiles of 64
#define NTILES 157  // M-tiles of 64

typedef __attribute__((ext_vector_type(8))) short short8x;
typedef __attribute__((ext_vector_type(4))) float f32x4;

__device__ __forceinline__ unsigned int bf16rne(float f){
  unsigned int u = __builtin_bit_cast(unsigned int, f);
  u += 0x7fffu + ((u >> 16) & 1u);   // round-to-nearest-even
  return u >> 16;
}
__device__ __forceinline__ float bf2f(unsigned short h){
  unsigned int u = ((unsigned int)h) << 16;
  return __builtin_bit_cast(float, u);
}
__device__ __forceinline__ void gload16(const void* g, void* l){
  __builtin_amdgcn_global_load_lds(
      (const __attribute__((address_space(1))) unsigned int*)g,
      (__attribute__((address_space(3))) unsigned int*)l, 16, 0, 0);
}

// ---------------- k_deg2 (UNCHANGED, measured 64us): one wave per FULL row.
__global__ __launch_bounds__(256) void k_deg2(const float* __restrict__ adj,
        float* __restrict__ degp){
  int t = threadIdx.x;
  int lane = t & 63;
  int row = blockIdx.x * 4 + (t >> 6);
  const f32x4* src = (const f32x4*)(adj + (size_t)row * NROW);
  const f32x4 zero4 = {0.f, 0.f, 0.f, 0.f};
  f32x4 acc0 = zero4, acc1 = zero4;
  f32x4 v[8];
  #pragma unroll
  for (int it = 0; it < 4; ++it){
    int base = it * 512 + lane;
    #pragma unroll
    for (int b = 0; b < 8; ++b) v[b] = src[base + b * 64];
    #pragma unroll
    for (int b = 0; b < 4; ++b){ acc0 += v[2*b]; acc1 += v[2*b + 1]; }
  }
  {
    int base = 2048 + lane;
    #pragma unroll
    for (int b = 0; b < 8; ++b){
      int fi = base + b * 64;
      v[b] = (fi < 2500) ? src[fi] : zero4;
    }
    #pragma unroll
    for (int b = 0; b < 4; ++b){ acc0 += v[2*b]; acc1 += v[2*b + 1]; }
  }
  f32x4 a = acc0 + acc1;
  float s = (a[0] + a[1]) + (a[2] + a[3]);
  #pragma unroll
  for (int off = 32; off; off >>= 1) s += __shfl_down(s, off);
  if (lane == 0) degp[row] = s;
}

// ---------------- k_dinv: dinv from raw rowsum (diag corrected); zero hsT tail.
__global__ void k_dinv(const float* __restrict__ degp, const float* __restrict__ adj,
                       float* __restrict__ dinv, unsigned short* __restrict__ hsT){
  int i = blockIdx.x * 256 + threadIdx.x;
  if (i >= MP) return;
  float d = 0.f;
  if (i < NROW){
    float tot = degp[i] + 1.0f - adj[(size_t)i * NROW + i];
    d = tot > 0.f ? rsqrtf(tot) : 0.f;
  }
  dinv[i] = d;
  if (i < NF){
    unsigned int* tz = (unsigned int*)(hsT + (size_t)i * MP + NROW);
    #pragma unroll
    for (int m = 0; m < (MP - NROW) / 2; ++m) tz[m] = 0u;
  }
}

// ---------------- k_featw (UNCHANGED): hsT[c][i] = bf16(dinv[i]*(feat@W)[i][c])
__global__ __launch_bounds__(128) void k_featw(const float* __restrict__ feat,
        const float* __restrict__ W, const float* __restrict__ dinv,
        unsigned short* __restrict__ hsT){
  __shared__ __align__(16) float fs[8][512];
  int t = threadIdx.x;
  int i0 = blockIdx.x * 8;
  #pragma unroll
  for (int it = 0; it < 8; ++it){
    int idx = it * 128 + t;
    int r = idx >> 7, c4 = (idx & 127) * 4;
    *(float4*)&fs[r][c4] = *(const float4*)(feat + (size_t)(i0 + r) * KF + c4);
  }
  __syncthreads();
  float acc[8][2];
  #pragma unroll
  for (int r = 0; r < 8; ++r){ acc[r][0] = 0.f; acc[r][1] = 0.f; }
  int c0 = t, c1 = t + 128;
  for (int k = 0; k < KF; k += 4){
    const float* Wk = W + (size_t)k * NF;
    float w0a = Wk[c0],        w0b = Wk[c1];
    float w1a = Wk[NF + c0],   w1b = Wk[NF + c1];
    float w2a = Wk[2*NF + c0], w2b = Wk[2*NF + c1];
    float w3a = Wk[3*NF + c0], w3b = Wk[3*NF + c1];
    #pragma unroll
    for (int r = 0; r < 8; ++r){
      float4 f = *(const float4*)&fs[r][k];
      float a0 = acc[r][0], a1 = acc[r][1];
      a0 = fmaf(f.x, w0a, a0); a1 = fmaf(f.x, w0b, a1);
      a0 = fmaf(f.y, w1a, a0); a1 = fmaf(f.y, w1b, a1);
      a0 = fmaf(f.z, w2a, a0); a1 = fmaf(f.z, w2b, a1);
      a0 = fmaf(f.w, w3a, a0); a1 = fmaf(f.w, w3b, a1);
      acc[r][0] = a0; acc[r][1] = a1;
    }
  }
  float dv[8];
  #pragma unroll
  for (int r = 0; r < 8; ++r) dv[r] = dinv[i0 + r];
  unsigned short* d0 = hsT + (size_t)c0 * MP + i0;
  unsigned short* d1 = hsT + (size_t)c1 * MP + i0;
  #pragma unroll
  for (int r = 0; r < 8; r += 2){
    unsigned int u0 = bf16rne(acc[r][0] * dv[r]) | (bf16rne(acc[r+1][0] * dv[r+1]) << 16);
    unsigned int u1 = bf16rne(acc[r][1] * dv[r]) | (bf16rne(acc[r+1][1] * dv[r+1]) << 16);
    *(unsigned int*)(d0 + r) = u0;
    *(unsigned int*)(d1 + r) = u1;
  }
}

// ---------------- k_gemm: 2-phase pipelined (global_load_lds A dbuf, raw
// s_barrier, counted auto-vmcnt). A f32 in LDS (XOR-swizzled), converted to
// bf16 at fragment read. Raw adj streamed (diag fixed in k_epi). Partial
// outputs per K-chunk (no atomics).
__global__ __launch_bounds__(256, 2) void k_gemm(const float* __restrict__ adj,
        const unsigned short* __restrict__ hsT, float* __restrict__ part){
  __shared__ __align__(16) float Afs[2][4096];           // 2 x 16KB, swizzled
  __shared__ __align__(16) unsigned short Bl[256][72];   // 36KB, +8 pad
  int t = threadIdx.x;
  int lane = t & 63, wid = t >> 6;
  int wr = wid >> 1, wc = wid & 1;      // 2x2 waves, wave tile 32x128
  int l15 = lane & 15, hi = lane >> 4;
  int r0 = blockIdx.x * 64;
  int by = blockIdx.y;                  // K chunks {40,39,39,39}
  int kt0 = by * 39 + (by > 0 ? 1 : 0);
  int kt1 = (by + 1) * 39 + 1;
  int ktf = kt1 < NKT ? kt1 : NKT - 1;  // tile 156 handled conventionally

  f32x4 acc[2][8];
  #pragma unroll
  for (int a = 0; a < 2; ++a)
    #pragma unroll
    for (int b = 0; b < 8; ++b)
      #pragma unroll
      for (int j = 0; j < 4; ++j) acc[a][b][j] = 0.f;

  // A-stage precompute: thread t stages LDS f32 slots adstoff[j] (linear,
  // wave-uniform-base + lane*16) from pre-swizzled global source.
  const float* asrc[4];
  int adstoff[4];
  {
    int srow = (wid << 2) + hi;         // + j*16
    #pragma unroll
    for (int j = 0; j < 4; ++j){
      int row = j * 16 + srow;
      int gr  = r0 + row;
      int er  = gr < NROW ? gr : NROW - 1;
      int logf = ((l15 * 16) ^ ((row & 7) << 4)) >> 2;   // inverse swizzle
      asrc[j] = adj + (size_t)er * NROW + logf;
      adstoff[j] = (j * 4096 + wid * 1024 + lane * 16) >> 2;
    }
  }
  int bcol = t >> 3;          // 0..31
  int bko  = (t & 7) * 8;     // 0..56

  #define STAGE_A(buf, k0g) { \
    _Pragma("unroll") \
    for (int j = 0; j < 4; ++j) \
      gload16(asrc[j] + (k0g), &Afs[buf][adstoff[j]]); }

  // fragment read: 8 f32 (logical) from swizzled LDS -> bf16 short8x
  #define LDA_FRAG(dst, buf, rowv, kk) { \
    int row_ = (rowv); \
    int sw_  = (row_ & 7) << 4; \
    const char* rp_ = (const char*)&Afs[buf][row_ * 64]; \
    int b0_ = (kk) * 128 + hi * 32; \
    f32x4 lo_ = *(const f32x4*)(rp_ + ((b0_     ) ^ sw_)); \
    f32x4 hh_ = *(const f32x4*)(rp_ + ((b0_ + 16) ^ sw_)); \
    union { unsigned int u[4]; short8x s; } cv_; \
    cv_.u[0] = bf16rne(lo_[0]) | (bf16rne(lo_[1]) << 16); \
    cv_.u[1] = bf16rne(lo_[2]) | (bf16rne(lo_[3]) << 16); \
    cv_.u[2] = bf16rne(hh_[0]) | (bf16rne(hh_[1]) << 16); \
    cv_.u[3] = bf16rne(hh_[2]) | (bf16rne(hh_[3]) << 16); \
    dst = cv_.s; }

  #define COMPUTE(buf) { \
    _Pragma("unroll") \
    for (int kk = 0; kk < 2; ++kk){ \
      short8x a0_, a1_; \
      LDA_FRAG(a0_, buf, wr*32      + l15, kk); \
      LDA_FRAG(a1_, buf, wr*32 + 16 + l15, kk); \
      _Pragma("unroll") \
      for (int ni = 0; ni < 8; ++ni){ \
        short8x b_ = *(const short8x*)&Bl[wc*128 + ni*16 + l15][kk*32 + hi*8]; \
        acc[0][ni] = __builtin_amdgcn_mfma_f32_16x16x32_bf16(a0_, b_, acc[0][ni], 0, 0, 0); \
        acc[1][ni] = __builtin_amdgcn_mfma_f32_16x16x32_bf16(a1_, b_, acc[1][ni], 0, 0, 0); \
      } \
    } }

  int cur = 0;
  STAGE_A(0, kt0 * 64);                 // prologue: A(kt0) in flight
  for (int kt = kt0; kt < ktf; ++kt){
    int k0 = kt * 64;
    uint4 bb[8];
    #pragma unroll
    for (int it = 0; it < 8; ++it)
      bb[it] = *(const uint4*)(hsT + (size_t)(it*32 + bcol) * MP + k0 + bko);
    __builtin_amdgcn_sched_barrier(0);
    if (kt + 1 < ktf) STAGE_A(cur ^ 1, k0 + 64);   // A(next): stays in flight
    __builtin_amdgcn_sched_barrier(0);
    #pragma unroll
    for (int it = 0; it < 8; ++it)      // compiler emits counted vmcnt here:
      *(uint4*)&Bl[it*32 + bcol][bko] = bb[it];  // drains B+A(cur), not A(next)
    asm volatile("s_waitcnt lgkmcnt(0)\ns_barrier" ::: "memory");
    COMPUTE(cur);
    asm volatile("s_barrier" ::: "memory");
    cur ^= 1;
  }
  if (kt1 == NKT){                      // tail tile 156 (cols 9984..10047)
    int k0 = (NKT - 1) * 64;
    #pragma unroll
    for (int s4 = 0; s4 < 4; ++s4){
      int slot = s4 * 256 + t;
      int row = slot >> 4;
      int physb = (slot & 15) * 16;
      int logb  = physb ^ ((row & 7) << 4);
      int gr = r0 + row;
      int er = gr < NROW ? gr : NROW - 1;
      int gc = k0 + (logb >> 2);
      int ec = gc <= NROW - 4 ? gc : NROW - 4;    // clamp; garbage x B==0
      f32x4 v = *(const f32x4*)(adj + (size_t)er * NROW + ec);
      *(f32x4*)((char*)&Afs[cur][row * 64] + physb) = v;
    }
    #pragma unroll
    for (int it = 0; it < 8; ++it)
      *(uint4*)&Bl[it*32 + bcol][bko] =
          *(const uint4*)(hsT + (size_t)(it*32 + bcol) * MP + k0 + bko);
    __syncthreads();
    COMPUTE(cur);
  }
  // epilogue: plain stores to this K-chunk's partial buffer
  float* pb = part + (size_t)by * ((size_t)MP * NF);
  #pragma unroll
  for (int mi = 0; mi < 2; ++mi){
    #pragma unroll
    for (int ni = 0; ni < 8; ++ni){
      int gc = wc*128 + ni*16 + l15;
      #pragma unroll
      for (int j = 0; j < 4; ++j){
        int gr = r0 + wr*32 + mi*16 + hi*4 + j;
        if (gr < NROW) pb[(size_t)gr * NF + gc] = acc[mi][ni][j];
      }
    }
  }
  #undef STAGE_A
  #undef LDA_FRAG
  #undef COMPUTE
}

// ---------------- k_epi: out = relu(dinv_i*(p0+p1+p2+p3 + (1-bf16(aii))*hsT) + b)
__global__ void k_epi(const float* __restrict__ part, const float* __restrict__ adj,
                      const unsigned short* __restrict__ hsT,
                      const float* __restrict__ dinv, const float* __restrict__ cb,
                      const float* __restrict__ eb, float* __restrict__ out){
  int e = (blockIdx.x * 256 + threadIdx.x) * 4;
  int i = e >> 8, c = e & 255;
  const size_t PS = (size_t)MP * NF;
  size_t o = (size_t)i * NF + c;
  float4 s0 = *(const float4*)(part + o);
  float4 s1 = *(const float4*)(part + PS + o);
  float4 s2 = *(const float4*)(part + 2*PS + o);
  float4 s3 = *(const float4*)(part + 3*PS + o);
  float sx = (s0.x + s1.x) + (s2.x + s3.x);
  float sy = (s0.y + s1.y) + (s2.y + s3.y);
  float sz = (s0.z + s1.z) + (s2.z + s3.z);
  float sw = (s0.w + s1.w) + (s2.w + s3.w);
  float aii = adj[(size_t)i * NROW + i];
  float av  = __builtin_bit_cast(float, bf16rne(aii) << 16);
  float w   = 1.0f - av;                 // diag correction weight
  sx += w * bf2f(hsT[(size_t)(c+0) * MP + i]);
  sy += w * bf2f(hsT[(size_t)(c+1) * MP + i]);
  sz += w * bf2f(hsT[(size_t)(c+2) * MP + i]);
  sw += w * bf2f(hsT[(size_t)(c+3) * MP + i]);
  float di = dinv[i];
  float4 r;
  r.x = fmaxf(fmaf(sx, di, cb[c+0] + eb[c+0]), 0.f);
  r.y = fmaxf(fmaf(sy, di, cb[c+1] + eb[c+1]), 0.f);
  r.z = fmaxf(fmaf(sz, di, cb[c+2] + eb[c+2]), 0.f);
  r.w = fmaxf(fmaf(sw, di, cb[c+3] + eb[c+3]), 0.f);
  *(float4*)(out + e) = r;
}

extern "C" void kernel_launch(void* const* d_in, const int* in_sizes, int n_in,
                              void* d_out, int out_size, void* d_ws, size_t ws_size,
                              hipStream_t stream){
  const float* feat = (const float*)d_in[0];
  const float* adj  = (const float*)d_in[1];
  const float* W    = (const float*)d_in[2];
  const float* cb   = (const float*)d_in[3];
  const float* eb   = (const float*)d_in[4];
  float* out = (float*)d_out;

  // ws: degp @0 ; dinv @256KB ; hsT bf16[256][10048] @512KB (5.15MB) ;
  //     part f32[4][10048][256] @8MB (41.2MB)
  float* degp = (float*)d_ws;
  float* dinv = (float*)((char*)d_ws + (256u << 10));
  unsigned short* hsT = (unsigned short*)((char*)d_ws + (512u << 10));
  float* part = (float*)((char*)d_ws + (8u << 20));

  k_deg2 <<<NROW/4,           256, 0, stream>>>(adj, degp);
  k_dinv <<<(MP + 255)/256,   256, 0, stream>>>(degp, adj, dinv, hsT);
  k_featw<<<NROW/8,           128, 0, stream>>>(feat, W, dinv, hsT);
  k_gemm <<<dim3(NTILES, 4),  256, 0, stream>>>(adj, hsT, part);
  k_epi  <<<(NROW*NF)/1024,   256, 0, stream>>>(part, adj, hsT, dinv, cb, eb, out);
}

// Round 16
// 281.359 us; speedup vs baseline: 1.6719x; 1.1315x over previous
//
#include <hip/hip_runtime.h>

#define NROW 10000
#define NF 256
#define KF 512
#define MP 10048   // padded row/K extent (157*64)
#define NTILES 157

typedef __attribute__((ext_vector_type(8))) short short8x;
typedef __attribute__((ext_vector_type(4))) float f32x4;

__device__ __forceinline__ unsigned int bf16rne(float f){
  unsigned int u = __builtin_bit_cast(unsigned int, f);
  u += 0x7fffu + ((u >> 16) & 1u);   // round-to-nearest-even
  return u >> 16;
}

// ---------------- Kernel 0: zero d_out (atomic accumulation target)
__global__ void k_zero(float4* __restrict__ p){
  p[blockIdx.x * 256 + threadIdx.x] = make_float4(0.f, 0.f, 0.f, 0.f);
}

// ---------------- k_prep3: fused degree + bf16 convert, deg2-row structure.
// One wave per FULL row (2500 blocks x 4 waves). 5 iterations of
// {8 nontemporal loads back-to-back -> patch diag/sum -> 4 uint4 stores}:
// per-wave quantum 40KB read / 20KB write, load(i+1)/store(i) overlap.
//   adjb[r][k] = bf16(Ahat[r][k])  (diag=1, cols>=10000 zeroed, k<10048)
//   degp[r]    = patched row sum (== degree)
__global__ __launch_bounds__(256) void k_prep3(const float* __restrict__ adj,
        unsigned short* __restrict__ adjb, float* __restrict__ degp){
  int t = threadIdx.x, lane = t & 63;
  int row = blockIdx.x * 4 + (t >> 6);          // 2500*4 = 10000 exact
  const f32x4* src = (const f32x4*)(adj + (size_t)row * NROW);  // 2500 slots
  unsigned short* dst = adjb + (size_t)row * MP;                // 2512 slots
  const f32x4 zero4 = {0.f, 0.f, 0.f, 0.f};
  f32x4 sacc = zero4;

  for (int it = 0; it < 5; ++it){
    int base = it * 512 + lane * 2;             // even f32x4 slot
    f32x4 v[8];
    // 8 loads issued back-to-back (pairs at 4 stride-128 points)
    #pragma unroll
    for (int s = 0; s < 4; ++s){
      int fi = base + s * 128;
      v[2*s]   = (fi     < 2500) ? __builtin_nontemporal_load(src + fi)     : zero4;
      v[2*s+1] = (fi + 1 < 2500) ? __builtin_nontemporal_load(src + fi + 1) : zero4;
    }
    // patch diag, accumulate degree, convert, store 16B per sub-batch
    #pragma unroll
    for (int s = 0; s < 4; ++s){
      int fi = base + s * 128;
      int gc0 = fi * 4, gc1 = gc0 + 4;
      f32x4 w0 = v[2*s], w1 = v[2*s+1];
      if (row == gc0    ) w0[0] = 1.f;
      if (row == gc0 + 1) w0[1] = 1.f;
      if (row == gc0 + 2) w0[2] = 1.f;
      if (row == gc0 + 3) w0[3] = 1.f;
      if (row == gc1    ) w1[0] = 1.f;
      if (row == gc1 + 1) w1[1] = 1.f;
      if (row == gc1 + 2) w1[2] = 1.f;
      if (row == gc1 + 3) w1[3] = 1.f;
      sacc += w0; sacc += w1;
      uint4 o;
      o.x = bf16rne(w0[0]) | (bf16rne(w0[1]) << 16);
      o.y = bf16rne(w0[2]) | (bf16rne(w0[3]) << 16);
      o.z = bf16rne(w1[0]) | (bf16rne(w1[1]) << 16);
      o.w = bf16rne(w1[2]) | (bf16rne(w1[3]) << 16);
      if (fi < 2512) *(uint4*)(dst + gc0) = o;  // covers K-pad zeros too
    }
  }
  float s = (sacc[0] + sacc[1]) + (sacc[2] + sacc[3]);
  #pragma unroll
  for (int off = 32; off; off >>= 1) s += __shfl_down(s, off);
  if (lane == 0) degp[row] = s;                 // unique slot: deterministic
}

// ---------------- k_dinv: dinv[i] = rsqrt(deg); zero hsT K-tail rows
__global__ void k_dinv(const float* __restrict__ degp, float* __restrict__ dinv,
                       unsigned short* __restrict__ hsT){
  int i = blockIdx.x * 256 + threadIdx.x;
  if (i >= MP) return;
  float d = 0.f;
  if (i < NROW){
    float tot = degp[i];                        // already diag-patched
    d = tot > 0.f ? rsqrtf(tot) : 0.f;
  }
  dinv[i] = d;
  if (i < NF){                 // zero hsT[i][10000..10048)
    unsigned int* tz = (unsigned int*)(hsT + (size_t)i * MP + NROW);
    #pragma unroll
    for (int m = 0; m < (MP - NROW) / 2; ++m) tz[m] = 0u;
  }
}

// ---------------- k_featw (UNCHANGED): hsT[c][i] = bf16(dinv[i]*(feat@W)[i][c])
__global__ __launch_bounds__(128) void k_featw(const float* __restrict__ feat,
        const float* __restrict__ W, const float* __restrict__ dinv,
        unsigned short* __restrict__ hsT){
  __shared__ __align__(16) float fs[8][512];   // 16 KB
  int t = threadIdx.x;        // 0..127
  int i0 = blockIdx.x * 8;    // 1250*8 = 10000 exact
  #pragma unroll
  for (int it = 0; it < 8; ++it){
    int idx = it * 128 + t;
    int r = idx >> 7, c4 = (idx & 127) * 4;
    *(float4*)&fs[r][c4] = *(const float4*)(feat + (size_t)(i0 + r) * KF + c4);
  }
  __syncthreads();
  float acc[8][2];
  #pragma unroll
  for (int r = 0; r < 8; ++r){ acc[r][0] = 0.f; acc[r][1] = 0.f; }
  int c0 = t, c1 = t + 128;
  for (int k = 0; k < KF; k += 4){
    const float* Wk = W + (size_t)k * NF;
    float w0a = Wk[c0],        w0b = Wk[c1];
    float w1a = Wk[NF + c0],   w1b = Wk[NF + c1];
    float w2a = Wk[2*NF + c0], w2b = Wk[2*NF + c1];
    float w3a = Wk[3*NF + c0], w3b = Wk[3*NF + c1];
    #pragma unroll
    for (int r = 0; r < 8; ++r){
      float4 f = *(const float4*)&fs[r][k];
      float a0 = acc[r][0], a1 = acc[r][1];
      a0 = fmaf(f.x, w0a, a0); a1 = fmaf(f.x, w0b, a1);
      a0 = fmaf(f.y, w1a, a0); a1 = fmaf(f.y, w1b, a1);
      a0 = fmaf(f.z, w2a, a0); a1 = fmaf(f.z, w2b, a1);
      a0 = fmaf(f.w, w3a, a0); a1 = fmaf(f.w, w3b, a1);
      acc[r][0] = a0; acc[r][1] = a1;
    }
  }
  float dv[8];
  #pragma unroll
  for (int r = 0; r < 8; ++r) dv[r] = dinv[i0 + r];
  unsigned short* d0 = hsT + (size_t)c0 * MP + i0;
  unsigned short* d1 = hsT + (size_t)c1 * MP + i0;
  #pragma unroll
  for (int r = 0; r < 8; r += 2){
    unsigned int u0 = bf16rne(acc[r][0] * dv[r]) | (bf16rne(acc[r+1][0] * dv[r+1]) << 16);
    unsigned int u1 = bf16rne(acc[r][1] * dv[r]) | (bf16rne(acc[r+1][1] * dv[r+1]) << 16);
    *(unsigned int*)(d0 + r) = u0;
    *(unsigned int*)(d1 + r) = u1;
  }
}

// ---------------- k_gemm (VERBATIM R8, measured ~88us): out += adjb @ hs
// K split 4-ways, atomic accumulate; 3 blocks/CU.
__global__ __launch_bounds__(256, 3) void k_gemm(const unsigned short* __restrict__ adjb,
        const unsigned short* __restrict__ hsT, float* __restrict__ out){
  __shared__ __align__(16) unsigned short Al[64][72];    // +8 pad: 144B stride
  __shared__ __align__(16) unsigned short Bl[256][72];
  int t = threadIdx.x;
  int lane = t & 63, wid = t >> 6;
  int wr = wid >> 1, wc = wid & 1;      // 2x2 waves, wave tile 32x128
  int r0 = blockIdx.x * 64;
  int by = blockIdx.y;                  // K chunks of {40,39,39,39} tiles
  int kt0 = by * 39 + (by > 0 ? 1 : 0);
  int kt1 = (by + 1) * 39 + 1;

  f32x4 acc[2][8];
  #pragma unroll
  for (int a = 0; a < 2; ++a)
    #pragma unroll
    for (int b = 0; b < 8; ++b)
      #pragma unroll
      for (int j = 0; j < 4; ++j) acc[a][b][j] = 0.f;

  int bcol = t >> 3;          // 0..31
  int bko  = (t & 7) * 8;     // 0..56

  for (int kt = kt0; kt < kt1; ++kt){
    int k0 = kt * 64;
    #pragma unroll
    for (int it = 0; it < 2; ++it){
      int slot = it * 256 + t;
      int row = slot >> 3, off8 = (slot & 7) * 8;
      *(uint4*)&Al[row][off8] =
          *(const uint4*)(adjb + (size_t)(r0 + row) * MP + k0 + off8);
    }
    #pragma unroll
    for (int it = 0; it < 8; ++it){
      int cc = it * 32 + bcol;
      *(uint4*)&Bl[cc][bko] = *(const uint4*)(hsT + (size_t)cc * MP + k0 + bko);
    }
    __syncthreads();
    #pragma unroll
    for (int kk = 0; kk < 64; kk += 32){
      short8x a0 = *(const short8x*)&Al[wr*32      + (lane & 15)][kk + (lane >> 4) * 8];
      short8x a1 = *(const short8x*)&Al[wr*32 + 16 + (lane & 15)][kk + (lane >> 4) * 8];
      #pragma unroll
      for (int ni = 0; ni < 8; ++ni){
        short8x b = *(const short8x*)&Bl[wc*128 + ni*16 + (lane & 15)][kk + (lane >> 4) * 8];
        acc[0][ni] = __builtin_amdgcn_mfma_f32_16x16x32_bf16(a0, b, acc[0][ni], 0, 0, 0);
        acc[1][ni] = __builtin_amdgcn_mfma_f32_16x16x32_bf16(a1, b, acc[1][ni], 0, 0, 0);
      }
    }
    __syncthreads();
  }
  #pragma unroll
  for (int mi = 0; mi < 2; ++mi){
    #pragma unroll
    for (int ni = 0; ni < 8; ++ni){
      int gc = wc*128 + ni*16 + (lane & 15);
      #pragma unroll
      for (int j = 0; j < 4; ++j){
        int gr = r0 + wr*32 + mi*16 + (lane >> 4) * 4 + j;
        if (gr < NROW) atomicAdd(out + (size_t)gr * NF + gc, acc[mi][ni][j]);
      }
    }
  }
}

// ---------------- k_epi: out = relu(dinv_i * acc + cb + eb), in place
__global__ void k_epi(float* __restrict__ out, const float* __restrict__ dinv,
                      const float* __restrict__ cb, const float* __restrict__ eb){
  int e = (blockIdx.x * 256 + threadIdx.x) * 4;
  int i = e >> 8, c = e & 255;
  float di = dinv[i];
  float4 v = *(float4*)(out + e);
  v.x = fmaxf(fmaf(v.x, di, cb[c+0] + eb[c+0]), 0.f);
  v.y = fmaxf(fmaf(v.y, di, cb[c+1] + eb[c+1]), 0.f);
  v.z = fmaxf(fmaf(v.z, di, cb[c+2] + eb[c+2]), 0.f);
  v.w = fmaxf(fmaf(v.w, di, cb[c+3] + eb[c+3]), 0.f);
  *(float4*)(out + e) = v;
}

extern "C" void kernel_launch(void* const* d_in, const int* in_sizes, int n_in,
                              void* d_out, int out_size, void* d_ws, size_t ws_size,
                              hipStream_t stream){
  const float* feat = (const float*)d_in[0];
  const float* adj  = (const float*)d_in[1];
  const float* W    = (const float*)d_in[2];
  const float* cb   = (const float*)d_in[3];
  const float* eb   = (const float*)d_in[4];
  float* out = (float*)d_out;

  // ws layout: degp f32[10048] @0 ; dinv f32[10048] @256KB ;
  //            hsT bf16[256][10048] @512KB (5.15MB) ;
  //            adjb bf16[10048][10048] @8MB (202MB).
  float* degp = (float*)d_ws;
  float* dinv = (float*)((char*)d_ws + (256u << 10));
  unsigned short* hsT  = (unsigned short*)((char*)d_ws + (512u << 10));
  unsigned short* adjb = (unsigned short*)((char*)d_ws + (8u << 20));

  k_zero <<<(NROW*NF)/1024,  256, 0, stream>>>((float4*)out);
  k_prep3<<<NROW/4,          256, 0, stream>>>(adj, adjb, degp);
  k_dinv <<<(MP + 255)/256,  256, 0, stream>>>(degp, dinv, hsT);
  k_featw<<<NROW/8,          128, 0, stream>>>(feat, W, dinv, hsT);
  k_gemm <<<dim3(NTILES, 4), 256, 0, stream>>>(adjb, hsT, out);
  k_epi  <<<(NROW*NF)/1024,  256, 0, stream>>>(out, dinv, cb, eb);
}